// Round 3
// baseline (712.739 us; speedup 1.0000x reference)
//
#include <hip/hip_runtime.h>
#include <float.h>

// EdgeConv: B=4, N=4096, Fin=64, Fout=64, K=20
// out[b,n,o] = u[b,n,o] + max_{m in knn20(n)} v[b,m,o]
//   u = x.(W1-W2)^T + bias ; v = x.W2^T
// knn on d = sq[n] + sq[m] - 2 x_n.x_m (>=0), self excluded.
//
// R3: K1 (u,v,sq) -> K2 (exact u16 keys to global, VALU GEMM w/ scalar
// n-operands) -> K3 (per-wave register bisection + exact recompute + tail).
// Fallback to R2's verified knn_kernel if ws_size can't hold the key buffer.

constexpr int Bb = 4, Nn = 4096, Ff = 64, Kk = 20;

// ---------------- K1: u, v, sq ----------------
constexpr int RT1 = 16;  // rows per block

__global__ __launch_bounds__(256) void uv_kernel2(
    const float* __restrict__ x, const float* __restrict__ W,
    const float* __restrict__ bvec, float* __restrict__ u,
    float* __restrict__ v, float* __restrict__ sq) {
  __shared__ __align__(16) float4 Ws[64 * 33];   // W row o at granules [33o,33o+32)
  __shared__ __align__(16) float4 xs[RT1 * 16];  // x row r at [16r..)
  const int t = threadIdx.x, l = t & 63, w = t >> 6;
  const int bn0 = blockIdx.x * RT1;
  #pragma unroll
  for (int i = 0; i < 8; i++) {
    int f = t + 256 * i;  // f4 index into W (64 rows x 32 f4)
    Ws[(f >> 5) * 33 + (f & 31)] = ((const float4*)W)[f];
  }
  xs[t] = ((const float4*)x)[bn0 * 16 + t];
  __syncthreads();
  // sq for rows 4w..4w+3
  #pragma unroll
  for (int i = 0; i < 4; i++) {
    int r = 4 * w + i;
    float val = ((const float*)&xs[r * 16])[l];
    float s = val * val;
    #pragma unroll
    for (int d = 32; d; d >>= 1) s += __shfl_xor(s, d, 64);
    if (l == 0) sq[bn0 + r] = s;
  }
  const int o = l;
  float ua[4] = {0.f, 0.f, 0.f, 0.f}, va[4] = {0.f, 0.f, 0.f, 0.f};
  #pragma unroll
  for (int c = 0; c < 16; c++) {
    float4 w1 = Ws[o * 33 + c];
    float4 w2 = Ws[o * 33 + 16 + c];
    float4 wd;
    wd.x = w1.x - w2.x; wd.y = w1.y - w2.y;
    wd.z = w1.z - w2.z; wd.w = w1.w - w2.w;
    #pragma unroll
    for (int i = 0; i < 4; i++) {
      float4 xv = xs[(4 * w + i) * 16 + c];
      ua[i] += xv.x * wd.x + xv.y * wd.y + xv.z * wd.z + xv.w * wd.w;
      va[i] += xv.x * w2.x + xv.y * w2.y + xv.z * w2.z + xv.w * w2.w;
    }
  }
  float bo = bvec[o];
  #pragma unroll
  for (int i = 0; i < 4; i++) {
    size_t row = (size_t)(bn0 + 4 * w + i);
    u[row * 64 + o] = ua[i] + bo;
    v[row * 64 + o] = va[i];
  }
}

// ---------------- K2: exact u16 keys to global ----------------
constexpr int NT2 = 32;   // n-rows per block
constexpr int MT2 = 128;  // m-rows per LDS tile
constexpr int GPR = 17;   // f4 granules per LDS tile row (16 + 1 pad)

__global__ __launch_bounds__(256) void key_kernel(
    const float* __restrict__ x, const float* __restrict__ sq,
    unsigned short* __restrict__ keys) {
  __shared__ __align__(16) float4 mtile[MT2 * GPR];  // 34816 B
  const int t = threadIdx.x;
  const int b = blockIdx.x >> 7;  // 128 n-blocks per batch
  const int n0 = (blockIdx.x & 127) * NT2;
  const int h = __builtin_amdgcn_readfirstlane(t >> 7);  // wave-uniform half
  const int lr = t & 127;                                // m-row within tile
  const float4* xb4 = (const float4*)(x + (size_t)b * Nn * Ff);
  const float* sqb = sq + b * Nn;
  const float4* xn4 = xb4 + (size_t)(n0 + 16 * h) * 16;  // uniform base
  for (int T = 0; T < Nn / MT2; ++T) {
    __syncthreads();
    #pragma unroll
    for (int i = 0; i < 8; i++) {
      int f = t + 256 * i;  // f4 index in tile (128 rows x 16 f4)
      mtile[(f >> 4) * GPR + (f & 15)] = xb4[T * (MT2 * 16) + f];
    }
    __syncthreads();
    float acc[16];
    #pragma unroll
    for (int r = 0; r < 16; r++) acc[r] = 0.f;
    #pragma unroll
    for (int c = 0; c < 16; c++) {
      float4 m4 = mtile[lr * GPR + c];
      #pragma unroll
      for (int r = 0; r < 16; r++) {
        float4 nv = xn4[r * 16 + c];  // wave-uniform -> s_load
        acc[r] += m4.x * nv.x + m4.y * nv.y + m4.z * nv.z + m4.w * nv.w;
      }
    }
    const int m = T * MT2 + lr;
    const float sm = sqb[m];
    #pragma unroll
    for (int r = 0; r < 16; r++) {
      int n = n0 + 16 * h + r;
      float d = fmaxf(sqb[n] + sm - 2.f * acc[r], 0.f);
      unsigned int key = __float_as_uint(d) >> 15;  // monotone, fits u16
      if (m == n) key = 0xFFFFu;
      keys[(size_t)(b * Nn + n) * Nn + m] = (unsigned short)key;
    }
  }
}

// ---------------- K3: selection + exact top-20 + output ----------------
__global__ __launch_bounds__(256) void select_kernel(
    const float* __restrict__ x, const unsigned short* __restrict__ keys,
    const float* __restrict__ u, const float* __restrict__ v,
    float* __restrict__ out) {
  __shared__ int candS[4 * 64];
  __shared__ int ccntS[4];
  const int t = threadIdx.x, l = t & 63, w = t >> 6;
  const int row = blockIdx.x * 4 + w;  // flat b*N+n
  const int rowu = __builtin_amdgcn_readfirstlane(row);
  const int b = rowu >> 12, n = rowu & (Nn - 1);
  const uint4* kr = (const uint4*)(keys + (size_t)rowu * Nn);
  uint4 kv[8];
  #pragma unroll
  for (int j = 0; j < 8; j++) kv[j] = kr[j * 64 + l];  // coalesced

  auto countLE = [&](int mid) -> int {
    int c = 0;
    #pragma unroll
    for (int j = 0; j < 8; j++) {
      unsigned int a0 = kv[j].x, a1 = kv[j].y, a2 = kv[j].z, a3 = kv[j].w;
      c += ((int)(a0 & 0xffffu) <= mid) + ((int)(a0 >> 16) <= mid);
      c += ((int)(a1 & 0xffffu) <= mid) + ((int)(a1 >> 16) <= mid);
      c += ((int)(a2 & 0xffffu) <= mid) + ((int)(a2 >> 16) <= mid);
      c += ((int)(a3 & 0xffffu) <= mid) + ((int)(a3 >> 16) <= mid);
    }
    #pragma unroll
    for (int d2 = 1; d2 < 64; d2 <<= 1) c += __shfl_xor(c, d2, 64);
    return c;
  };

  // lane-local min key, then wave min
  unsigned int mn = 0xffffffffu;
  #pragma unroll
  for (int j = 0; j < 8; j++) {
    unsigned int a0 = kv[j].x, a1 = kv[j].y, a2 = kv[j].z, a3 = kv[j].w;
    mn = min(mn, min(min(a0 & 0xffffu, a0 >> 16), min(a1 & 0xffffu, a1 >> 16)));
    mn = min(mn, min(min(a2 & 0xffffu, a2 >> 16), min(a3 & 0xffffu, a3 >> 16)));
  }
  #pragma unroll
  for (int d2 = 1; d2 < 64; d2 <<= 1)
    mn = min(mn, (unsigned int)__shfl_xor((int)mn, d2, 64));

  // gallop up from min, then bisect: invariant count(lo)<20<=count(hi)
  int lo = (int)mn - 1;
  int hi = (int)mn + 64;
  if (hi > 65534) hi = 65534;
  int c = countLE(hi);
  int step = 128;
  while (c < Kk) {
    lo = hi;
    hi += step;
    if (hi > 65534) hi = 65534;
    step <<= 1;
    c = countLE(hi);
  }
  while (c > 48 && hi - lo > 1) {
    int mid = (lo + hi) >> 1;
    int cm = countLE(mid);
    if (cm >= Kk) { hi = mid; c = cm; } else { lo = mid; }
  }

  // collect candidates (key <= hi); self key 0xFFFF never collected (hi<=65534)
  if (l == 0) ccntS[w] = 0;  // in-wave LDS ordering
  #pragma unroll
  for (int j = 0; j < 8; j++) {
    unsigned int a[4] = {kv[j].x, kv[j].y, kv[j].z, kv[j].w};
    #pragma unroll
    for (int e = 0; e < 4; e++) {
      int base = ((j * 64 + l) * 4 + e) * 2;
      if ((int)(a[e] & 0xffffu) <= hi) {
        int slot = atomicAdd(&ccntS[w], 1);
        if (slot < 64) candS[w * 64 + slot] = base;
      }
      if ((int)(a[e] >> 16) <= hi) {
        int slot = atomicAdd(&ccntS[w], 1);
        if (slot < 64) candS[w * 64 + slot] = base + 1;
      }
    }
  }
  int C = ccntS[w];
  if (C > 64) C = 64;

  // exact fp32 distance per candidate
  const float4* xb4 = (const float4*)(x + (size_t)b * Nn * Ff);
  unsigned long long key64 = ~0ULL;
  if (l < C) {
    int mI = candS[w * 64 + l];
    const float4* xmf = xb4 + (size_t)mI * 16;
    float ds = 0.f;
    #pragma unroll
    for (int cc = 0; cc < 16; cc++) {
      float4 a = xb4[(size_t)n * 16 + cc];  // wave-uniform
      float4 bb = xmf[cc];
      float dx = a.x - bb.x, dy = a.y - bb.y, dz = a.z - bb.z, dw2 = a.w - bb.w;
      ds += dx * dx + dy * dy + dz * dz + dw2 * dw2;
    }
    key64 = ((unsigned long long)__float_as_uint(ds) << 32) | (unsigned int)mI;
  }

  // 20 exact min-extractions fused with v-gather + max
  float vmax = -FLT_MAX;
  const float* vb = v + (size_t)b * Nn * Ff;
  #pragma unroll
  for (int it = 0; it < Kk; ++it) {
    unsigned long long kmin = key64;
    #pragma unroll
    for (int d2 = 1; d2 < 64; d2 <<= 1) {
      unsigned long long o =
          (unsigned long long)__shfl_xor((long long)kmin, d2, 64);
      kmin = (o < kmin) ? o : kmin;
    }
    int mI = (int)(kmin & 0xffffffffu);
    vmax = fmaxf(vmax, vb[(size_t)mI * 64 + l]);
    if (key64 == kmin) key64 = ~0ULL;
  }
  const size_t oidx = (size_t)rowu * 64 + l;
  out[oidx] = u[oidx] + vmax;
}

// ---------------- R2 fallback knn (verified) ----------------
constexpr int RTF = 4;
constexpr int MTF = 64;
constexpr int TPADF = 17;
constexpr int CCAPF = 64;

__global__ __launch_bounds__(256) void knn_kernel(
    const float* __restrict__ x, const float* __restrict__ sq,
    const float* __restrict__ u, const float* __restrict__ v,
    float* __restrict__ out) {
  __shared__ __align__(16) float4 tileS[MTF * TPADF];
  __shared__ __align__(16) unsigned short keysS[RTF * Nn];
  __shared__ int candS[RTF * CCAPF];
  __shared__ int ccntS[RTF];
  const int t = threadIdx.x;
  const int l = t & 63, w = t >> 6;
  const int q = l & 15, g = l >> 4;
  const int bn0 = blockIdx.x * RTF;
  const int b = bn0 >> 12;
  const int n0 = bn0 & (Nn - 1);
  const float4* xb4 = (const float4*)(x + (size_t)b * Nn * Ff);
  const float* sqb = sq + b * Nn;
  if (t < RTF) ccntS[t] = 0;
  float4 xnq[RTF][4];
  #pragma unroll
  for (int r = 0; r < RTF; r++)
    #pragma unroll
    for (int c = 0; c < 4; c++) xnq[r][c] = xb4[(n0 + r) * 16 + 4 * g + c];
  const float sn = sqb[n0 + g];
  const int selfm = n0 + g;
  for (int T = 0; T < Nn / MTF; ++T) {
    __syncthreads();
    #pragma unroll
    for (int i = 0; i < 4; i++) {
      int f = t + 256 * i;
      tileS[(f >> 4) * TPADF + (f & 15)] = xb4[T * 1024 + f];
    }
    __syncthreads();
    const int mrow = 16 * w + q;
    const float4* xmp = &tileS[mrow * TPADF + 4 * g];
    float4 xm0 = xmp[0], xm1 = xmp[1], xm2 = xmp[2], xm3 = xmp[3];
    float dot[RTF];
    #pragma unroll
    for (int r = 0; r < RTF; r++) {
      float4 a0 = xnq[r][0], a1 = xnq[r][1], a2 = xnq[r][2], a3 = xnq[r][3];
      dot[r] = a0.x * xm0.x + a0.y * xm0.y + a0.z * xm0.z + a0.w * xm0.w +
               a1.x * xm1.x + a1.y * xm1.y + a1.z * xm1.z + a1.w * xm1.w +
               a2.x * xm2.x + a2.y * xm2.y + a2.z * xm2.z + a2.w * xm2.w +
               a3.x * xm3.x + a3.y * xm3.y + a3.z * xm3.z + a3.w * xm3.w;
    }
    #pragma unroll
    for (int r = 0; r < RTF; r++) {
      dot[r] += __shfl_xor(dot[r], 16, 64);
      dot[r] += __shfl_xor(dot[r], 32, 64);
    }
    float dg = (g == 0) ? dot[0] : (g == 1) ? dot[1] : (g == 2) ? dot[2] : dot[3];
    int m = T * MTF + mrow;
    float d = fmaxf(fmaf(-2.f, dg, sqb[m] + sn), 0.f);
    unsigned int key = __float_as_uint(d) >> 15;
    if (m == selfm) key = 0xFFFFu;
    keysS[g * Nn + m] = (unsigned short)key;
  }
  __syncthreads();
  const unsigned int* kp = (const unsigned int*)&keysS[w * Nn];
  int lo = -1, hi = 65535, cntHi = Nn;
  while (cntHi > 48 && hi - lo > 1) {
    int mid = (lo + hi) >> 1;
    unsigned int midu = (unsigned int)mid;
    int c = 0;
    #pragma unroll
    for (int cc = 0; cc < 8; ++cc) {
      int rc = (cc + l) & 7;
      uint4 k4 = *(const uint4*)(kp + l * 32 + rc * 4);
      c += ((k4.x & 0xffffu) <= midu) + ((k4.x >> 16) <= midu);
      c += ((k4.y & 0xffffu) <= midu) + ((k4.y >> 16) <= midu);
      c += ((k4.z & 0xffffu) <= midu) + ((k4.z >> 16) <= midu);
      c += ((k4.w & 0xffffu) <= midu) + ((k4.w >> 16) <= midu);
    }
    #pragma unroll
    for (int d2 = 1; d2 < 64; d2 <<= 1) c += __shfl_xor(c, d2, 64);
    if (c >= Kk) { hi = mid; cntHi = c; } else { lo = mid; }
  }
  {
    unsigned int hu = (unsigned int)hi;
    #pragma unroll
    for (int cc = 0; cc < 8; ++cc) {
      int rc = (cc + l) & 7;
      uint4 k4 = *(const uint4*)(kp + l * 32 + rc * 4);
      unsigned int ks[4] = {k4.x, k4.y, k4.z, k4.w};
      #pragma unroll
      for (int uu = 0; uu < 4; ++uu) {
        #pragma unroll
        for (int hh = 0; hh < 2; ++hh) {
          unsigned int kvv = hh ? (ks[uu] >> 16) : (ks[uu] & 0xffffu);
          if (kvv <= hu) {
            int slot = atomicAdd(&ccntS[w], 1);
            if (slot < CCAPF) candS[w * CCAPF + slot] = l * 64 + (rc * 4 + uu) * 2 + hh;
          }
        }
      }
    }
  }
  __syncthreads();
  const int n = n0 + w;
  const int C = min(cntHi, CCAPF);
  unsigned long long key64 = ~0ULL;
  if (l < C) {
    int mI = candS[w * CCAPF + l];
    const float4* xmf = xb4 + mI * 16;
    float ds = 0.f;
    #pragma unroll
    for (int c = 0; c < 16; c++) {
      float4 a = xb4[n * 16 + c];
      float4 bb = xmf[c];
      float dx = a.x - bb.x, dy = a.y - bb.y, dz = a.z - bb.z, dw2 = a.w - bb.w;
      ds += dx * dx + dy * dy + dz * dz + dw2 * dw2;
    }
    key64 = ((unsigned long long)__float_as_uint(ds) << 32) | (unsigned int)mI;
  }
  float vmax = -FLT_MAX;
  const float* vb = v + (size_t)b * Nn * Ff;
  #pragma unroll
  for (int it = 0; it < Kk; ++it) {
    unsigned long long kmin = key64;
    #pragma unroll
    for (int d2 = 1; d2 < 64; d2 <<= 1) {
      unsigned long long o =
          (unsigned long long)__shfl_xor((long long)kmin, d2, 64);
      kmin = (o < kmin) ? o : kmin;
    }
    int mI = (int)(kmin & 0xffffffffu);
    vmax = fmaxf(vmax, vb[mI * 64 + l]);
    if (key64 == kmin) key64 = ~0ULL;
  }
  const size_t oidx = (size_t)(bn0 + w) * 64 + l;
  out[oidx] = u[oidx] + vmax;
}

extern "C" void kernel_launch(void* const* d_in, const int* in_sizes, int n_in,
                              void* d_out, int out_size, void* d_ws,
                              size_t ws_size, hipStream_t stream) {
  const float* x = (const float*)d_in[0];
  const float* W = (const float*)d_in[1];
  const float* bvec = (const float*)d_in[2];
  float* u = (float*)d_ws;                      // 4 MB
  float* v = u + (size_t)Bb * Nn * Ff;          // 4 MB
  float* sq = v + (size_t)Bb * Nn * Ff;         // 64 KB
  unsigned short* keys = (unsigned short*)(sq + (size_t)Bb * Nn);  // 128 MB
  float* out = (float*)d_out;
  const size_t need = (size_t)Bb * Nn * Ff * 4 * 2 + (size_t)Bb * Nn * 4 +
                      (size_t)Bb * Nn * Nn * 2;

  uv_kernel2<<<Bb * Nn / RT1, 256, 0, stream>>>(x, W, bvec, u, v, sq);
  if (ws_size >= need) {
    key_kernel<<<Bb * Nn / NT2, 256, 0, stream>>>(x, sq, keys);
    select_kernel<<<Bb * Nn / 4, 256, 0, stream>>>(x, keys, u, v, out);
  } else {
    knn_kernel<<<Bb * Nn / RTF, 256, 0, stream>>>(x, sq, u, v, out);
  }
}

// Round 5
// 205.276 us; speedup vs baseline: 3.4721x; 3.4721x over previous
//
#include <hip/hip_runtime.h>
#include <float.h>

// EdgeConv: B=4, N=4096, Fin=64, Fout=64, K=20
// out[b,n,o] = u[b,n,o] + max_{m in knn20(n)} v[b,m,o]
//   u = x.(W1-W2)^T + bias ; v = x.W2^T
// knn on d = sq[n] + sq[m] - 2 x_n.x_m (>=0), self excluded.
//
// R5 = R4 + fixes: key_mfma grid 256->1024 (batches 1..3 were uncovered!),
// bounded gallop loop in select (garbage keys can no longer hang the queue),
// masked gather index. Pipeline: K1 (u,v,sq,bf16 hi/lo) -> K2 (MFMA
// 32x32x16_bf16, 3-product hi/lo keys to global) -> K3 (bisect + exact
// recompute + top-20 + v-gather). R2's verified knn_kernel as ws fallback.

constexpr int Bb = 4, Nn = 4096, Ff = 64, Kk = 20;

typedef __attribute__((ext_vector_type(8))) short bf16x8;
typedef __attribute__((ext_vector_type(16))) float f32x16;

__device__ inline unsigned int bf16rn(float f) {
  unsigned int u = __float_as_uint(f);
  return (u + 0x7fffu + ((u >> 16) & 1u)) >> 16;
}

// ---------------- K1: u, v, sq, xhi, xlo ----------------
constexpr int RT1 = 16;  // rows per block

__global__ __launch_bounds__(256) void uv_kernel2(
    const float* __restrict__ x, const float* __restrict__ W,
    const float* __restrict__ bvec, float* __restrict__ u,
    float* __restrict__ v, float* __restrict__ sq,
    unsigned short* __restrict__ xhi, unsigned short* __restrict__ xlo) {
  __shared__ __align__(16) float4 Ws[64 * 33];   // W row o at granules [33o,33o+32)
  __shared__ __align__(16) float4 xs[RT1 * 16];  // x row r at [16r..)
  const int t = threadIdx.x, l = t & 63, w = t >> 6;
  const int bn0 = blockIdx.x * RT1;
  #pragma unroll
  for (int i = 0; i < 8; i++) {
    int f = t + 256 * i;  // f4 index into W (64 rows x 32 f4)
    Ws[(f >> 5) * 33 + (f & 31)] = ((const float4*)W)[f];
  }
  xs[t] = ((const float4*)x)[bn0 * 16 + t];
  __syncthreads();
  // bf16 hi/lo split (4 elements per thread)
  #pragma unroll
  for (int i = 0; i < 4; i++) {
    int idx = t + 256 * i;  // 0..1023 within block's 16 rows
    float val = ((const float*)xs)[idx];
    unsigned int hb = bf16rn(val);
    float fhi = __uint_as_float(hb << 16);
    unsigned int lb = bf16rn(val - fhi);
    size_t goff = (size_t)bn0 * 64 + idx;
    xhi[goff] = (unsigned short)hb;
    xlo[goff] = (unsigned short)lb;
  }
  // sq for rows 4w..4w+3
  #pragma unroll
  for (int i = 0; i < 4; i++) {
    int r = 4 * w + i;
    float val = ((const float*)&xs[r * 16])[l];
    float s = val * val;
    #pragma unroll
    for (int d = 32; d; d >>= 1) s += __shfl_xor(s, d, 64);
    if (l == 0) sq[bn0 + r] = s;
  }
  const int o = l;
  float ua[4] = {0.f, 0.f, 0.f, 0.f}, va[4] = {0.f, 0.f, 0.f, 0.f};
  #pragma unroll
  for (int c = 0; c < 16; c++) {
    float4 w1 = Ws[o * 33 + c];
    float4 w2 = Ws[o * 33 + 16 + c];
    float4 wd;
    wd.x = w1.x - w2.x; wd.y = w1.y - w2.y;
    wd.z = w1.z - w2.z; wd.w = w1.w - w2.w;
    #pragma unroll
    for (int i = 0; i < 4; i++) {
      float4 xv = xs[(4 * w + i) * 16 + c];
      ua[i] += xv.x * wd.x + xv.y * wd.y + xv.z * wd.z + xv.w * wd.w;
      va[i] += xv.x * w2.x + xv.y * w2.y + xv.z * w2.z + xv.w * w2.w;
    }
  }
  float bo = bvec[o];
  #pragma unroll
  for (int i = 0; i < 4; i++) {
    size_t row = (size_t)(bn0 + 4 * w + i);
    u[row * 64 + o] = ua[i] + bo;
    v[row * 64 + o] = va[i];
  }
}

// ---------------- K2: MFMA distance keys ----------------
// Per wave: 32 n-rows x 512 m-cols. Block = 4 waves (same n-tile, 2048 m).
// Grid: 4 batches x 128 n-tiles x 2 m-halves = 1024 blocks.
// A/B frag (32x32x16_bf16): lane holds row/col (l&31), 8 contiguous k at
// 8*(l>>5). C/D: col=lane&31, row=(reg&3)+8*(reg>>2)+4*(lane>>5) [m74/m101].

__global__ __launch_bounds__(256) void key_mfma_kernel(
    const unsigned short* __restrict__ xhi,
    const unsigned short* __restrict__ xlo, const float* __restrict__ sq,
    unsigned short* __restrict__ keys) {
  const int t = threadIdx.x, l = t & 63, w = t >> 6;
  const int blk = blockIdx.x;
  const int b = blk >> 8;
  const int r = blk & 255;
  const int n_base = (r >> 1) * 32;
  const int m0w = (r & 1) * 2048 + w * 512;
  const int col = l & 31, half = l >> 5;

  const unsigned short* xhb = xhi + (size_t)b * Nn * Ff;
  const unsigned short* xlb = xlo + (size_t)b * Nn * Ff;
  const float* sqb = sq + b * Nn;

  bf16x8 Ahi[4], Alo[4];
  #pragma unroll
  for (int ks = 0; ks < 4; ks++) {
    size_t off = (size_t)(n_base + col) * Ff + ks * 16 + half * 8;
    Ahi[ks] = *(const bf16x8*)(xhb + off);
    Alo[ks] = *(const bf16x8*)(xlb + off);
  }
  float sqn_r[16];
  #pragma unroll
  for (int e = 0; e < 16; e++) {
    int row = (e & 3) + 8 * (e >> 2) + 4 * half;
    sqn_r[e] = sqb[n_base + row];
  }

  for (int j = 0; j < 16; ++j) {
    const int m0 = m0w + 32 * j;
    bf16x8 Bhi[4], Blo[4];
    #pragma unroll
    for (int ks = 0; ks < 4; ks++) {
      size_t off = (size_t)(m0 + col) * Ff + ks * 16 + half * 8;
      Bhi[ks] = *(const bf16x8*)(xhb + off);
      Blo[ks] = *(const bf16x8*)(xlb + off);
    }
    f32x16 acc = {0.f, 0.f, 0.f, 0.f, 0.f, 0.f, 0.f, 0.f,
                  0.f, 0.f, 0.f, 0.f, 0.f, 0.f, 0.f, 0.f};
    #pragma unroll
    for (int ks = 0; ks < 4; ks++) {
      acc = __builtin_amdgcn_mfma_f32_32x32x16_bf16(Ahi[ks], Bhi[ks], acc, 0, 0, 0);
      acc = __builtin_amdgcn_mfma_f32_32x32x16_bf16(Ahi[ks], Blo[ks], acc, 0, 0, 0);
      acc = __builtin_amdgcn_mfma_f32_32x32x16_bf16(Alo[ks], Bhi[ks], acc, 0, 0, 0);
    }
    const int m = m0 + col;
    const float sm = sqb[m];
    #pragma unroll
    for (int e = 0; e < 16; e++) {
      int row = (e & 3) + 8 * (e >> 2) + 4 * half;
      int n = n_base + row;
      float d = fmaxf(sqn_r[e] + sm - 2.0f * acc[e], 0.f);
      unsigned int key = __float_as_uint(d) >> 15;
      if (m == n) key = 0xFFFFu;
      keys[((size_t)(b * Nn + n) << 12) + m] = (unsigned short)key;
    }
  }
}

// ---------------- K3: selection + exact top-20 + output ----------------
__global__ __launch_bounds__(256) void select_kernel(
    const float* __restrict__ x, const unsigned short* __restrict__ keys,
    const float* __restrict__ u, const float* __restrict__ v,
    float* __restrict__ out) {
  __shared__ int candS[4 * 64];
  __shared__ int ccntS[4];
  const int t = threadIdx.x, l = t & 63, w = t >> 6;
  const int row = blockIdx.x * 4 + w;  // flat b*N+n
  const int rowu = __builtin_amdgcn_readfirstlane(row);
  const int b = rowu >> 12, n = rowu & (Nn - 1);
  const uint4* kr = (const uint4*)(keys + (size_t)rowu * Nn);
  uint4 kv[8];
  #pragma unroll
  for (int j = 0; j < 8; j++) kv[j] = kr[j * 64 + l];  // coalesced

  auto countLE = [&](int mid) -> int {
    int c = 0;
    #pragma unroll
    for (int j = 0; j < 8; j++) {
      unsigned int a0 = kv[j].x, a1 = kv[j].y, a2 = kv[j].z, a3 = kv[j].w;
      c += ((int)(a0 & 0xffffu) <= mid) + ((int)(a0 >> 16) <= mid);
      c += ((int)(a1 & 0xffffu) <= mid) + ((int)(a1 >> 16) <= mid);
      c += ((int)(a2 & 0xffffu) <= mid) + ((int)(a2 >> 16) <= mid);
      c += ((int)(a3 & 0xffffu) <= mid) + ((int)(a3 >> 16) <= mid);
    }
    #pragma unroll
    for (int d2 = 1; d2 < 64; d2 <<= 1) c += __shfl_xor(c, d2, 64);
    return c;
  };

  unsigned int mn = 0xffffffffu;
  #pragma unroll
  for (int j = 0; j < 8; j++) {
    unsigned int a0 = kv[j].x, a1 = kv[j].y, a2 = kv[j].z, a3 = kv[j].w;
    mn = min(mn, min(min(a0 & 0xffffu, a0 >> 16), min(a1 & 0xffffu, a1 >> 16)));
    mn = min(mn, min(min(a2 & 0xffffu, a2 >> 16), min(a3 & 0xffffu, a3 >> 16)));
  }
  #pragma unroll
  for (int d2 = 1; d2 < 64; d2 <<= 1)
    mn = min(mn, (unsigned int)__shfl_xor((int)mn, d2, 64));

  // gallop up from min (BOUNDED: exits at cap even on degenerate key rows),
  // then bisect; invariant when c>=20: count(lo)<20<=count(hi)
  int lo = (int)mn - 1;
  int hi = (int)mn + 64;
  if (hi > 65534) hi = 65534;
  int c = countLE(hi);
  int step = 128;
  while (c < Kk && hi < 65534) {
    lo = hi;
    hi += step;
    if (hi > 65534) hi = 65534;
    step <<= 1;
    c = countLE(hi);
  }
  while (c > 44 && hi - lo > 1) {
    int mid = (lo + hi) >> 1;
    int cm = countLE(mid);
    if (cm >= Kk) { hi = mid; c = cm; } else { lo = mid; }
  }
  const int hc = hi + 1;  // +1 quantum margin for approx (bf16-split) keys

  if (l == 0) ccntS[w] = 0;  // in-wave LDS ordering
  #pragma unroll
  for (int j = 0; j < 8; j++) {
    unsigned int a[4] = {kv[j].x, kv[j].y, kv[j].z, kv[j].w};
    #pragma unroll
    for (int e = 0; e < 4; e++) {
      int base = ((j * 64 + l) * 4 + e) * 2;
      if ((int)(a[e] & 0xffffu) <= hc) {
        int slot = atomicAdd(&ccntS[w], 1);
        if (slot < 64) candS[w * 64 + slot] = base;
      }
      if ((int)(a[e] >> 16) <= hc) {
        int slot = atomicAdd(&ccntS[w], 1);
        if (slot < 64) candS[w * 64 + slot] = base + 1;
      }
    }
  }
  int C = ccntS[w];
  if (C > 64) C = 64;

  // exact fp32 distance per candidate
  const float4* xb4 = (const float4*)(x + (size_t)b * Nn * Ff);
  unsigned long long key64 = ~0ULL;
  if (l < C) {
    int mI = candS[w * 64 + l];
    const float4* xmf = xb4 + (size_t)mI * 16;
    float ds = 0.f;
    #pragma unroll
    for (int cc = 0; cc < 16; cc++) {
      float4 a = xb4[(size_t)n * 16 + cc];  // wave-uniform
      float4 bb = xmf[cc];
      float dx = a.x - bb.x, dy = a.y - bb.y, dz = a.z - bb.z, dw2 = a.w - bb.w;
      ds += dx * dx + dy * dy + dz * dz + dw2 * dw2;
    }
    if (mI == n) ds = FLT_MAX;  // belt-and-braces self exclusion
    key64 = ((unsigned long long)__float_as_uint(ds) << 32) | (unsigned int)mI;
  }

  // 20 exact min-extractions fused with v-gather + max
  float vmax = -FLT_MAX;
  const float* vb = v + (size_t)b * Nn * Ff;
  #pragma unroll
  for (int it = 0; it < Kk; ++it) {
    unsigned long long kmin = key64;
    #pragma unroll
    for (int d2 = 1; d2 < 64; d2 <<= 1) {
      unsigned long long o =
          (unsigned long long)__shfl_xor((long long)kmin, d2, 64);
      kmin = (o < kmin) ? o : kmin;
    }
    int mI = (int)(kmin & 0xffffffffu) & (Nn - 1);  // masked: can't fault
    vmax = fmaxf(vmax, vb[(size_t)mI * 64 + l]);
    if (key64 == kmin) key64 = ~0ULL;
  }
  const size_t oidx = (size_t)rowu * 64 + l;
  out[oidx] = u[oidx] + vmax;
}

// ---------------- R2 fallback knn (verified) ----------------
constexpr int RTF = 4;
constexpr int MTF = 64;
constexpr int TPADF = 17;
constexpr int CCAPF = 64;

__global__ __launch_bounds__(256) void knn_kernel(
    const float* __restrict__ x, const float* __restrict__ sq,
    const float* __restrict__ u, const float* __restrict__ v,
    float* __restrict__ out) {
  __shared__ __align__(16) float4 tileS[MTF * TPADF];
  __shared__ __align__(16) unsigned short keysS[RTF * Nn];
  __shared__ int candS[RTF * CCAPF];
  __shared__ int ccntS[RTF];
  const int t = threadIdx.x;
  const int l = t & 63, w = t >> 6;
  const int q = l & 15, g = l >> 4;
  const int bn0 = blockIdx.x * RTF;
  const int b = bn0 >> 12;
  const int n0 = bn0 & (Nn - 1);
  const float4* xb4 = (const float4*)(x + (size_t)b * Nn * Ff);
  const float* sqb = sq + b * Nn;
  if (t < RTF) ccntS[t] = 0;
  float4 xnq[RTF][4];
  #pragma unroll
  for (int r = 0; r < RTF; r++)
    #pragma unroll
    for (int c = 0; c < 4; c++) xnq[r][c] = xb4[(n0 + r) * 16 + 4 * g + c];
  const float sn = sqb[n0 + g];
  const int selfm = n0 + g;
  for (int T = 0; T < Nn / MTF; ++T) {
    __syncthreads();
    #pragma unroll
    for (int i = 0; i < 4; i++) {
      int f = t + 256 * i;
      tileS[(f >> 4) * TPADF + (f & 15)] = xb4[T * 1024 + f];
    }
    __syncthreads();
    const int mrow = 16 * w + q;
    const float4* xmp = &tileS[mrow * TPADF + 4 * g];
    float4 xm0 = xmp[0], xm1 = xmp[1], xm2 = xmp[2], xm3 = xmp[3];
    float dot[RTF];
    #pragma unroll
    for (int r = 0; r < RTF; r++) {
      float4 a0 = xnq[r][0], a1 = xnq[r][1], a2 = xnq[r][2], a3 = xnq[r][3];
      dot[r] = a0.x * xm0.x + a0.y * xm0.y + a0.z * xm0.z + a0.w * xm0.w +
               a1.x * xm1.x + a1.y * xm1.y + a1.z * xm1.z + a1.w * xm1.w +
               a2.x * xm2.x + a2.y * xm2.y + a2.z * xm2.z + a2.w * xm2.w +
               a3.x * xm3.x + a3.y * xm3.y + a3.z * xm3.z + a3.w * xm3.w;
    }
    #pragma unroll
    for (int r = 0; r < RTF; r++) {
      dot[r] += __shfl_xor(dot[r], 16, 64);
      dot[r] += __shfl_xor(dot[r], 32, 64);
    }
    float dg = (g == 0) ? dot[0] : (g == 1) ? dot[1] : (g == 2) ? dot[2] : dot[3];
    int m = T * MTF + mrow;
    float d = fmaxf(fmaf(-2.f, dg, sqb[m] + sn), 0.f);
    unsigned int key = __float_as_uint(d) >> 15;
    if (m == selfm) key = 0xFFFFu;
    keysS[g * Nn + m] = (unsigned short)key;
  }
  __syncthreads();
  const unsigned int* kp = (const unsigned int*)&keysS[w * Nn];
  int lo = -1, hi = 65535, cntHi = Nn;
  while (cntHi > 48 && hi - lo > 1) {
    int mid = (lo + hi) >> 1;
    unsigned int midu = (unsigned int)mid;
    int c = 0;
    #pragma unroll
    for (int cc = 0; cc < 8; ++cc) {
      int rc = (cc + l) & 7;
      uint4 k4 = *(const uint4*)(kp + l * 32 + rc * 4);
      c += ((k4.x & 0xffffu) <= midu) + ((k4.x >> 16) <= midu);
      c += ((k4.y & 0xffffu) <= midu) + ((k4.y >> 16) <= midu);
      c += ((k4.z & 0xffffu) <= midu) + ((k4.z >> 16) <= midu);
      c += ((k4.w & 0xffffu) <= midu) + ((k4.w >> 16) <= midu);
    }
    #pragma unroll
    for (int d2 = 1; d2 < 64; d2 <<= 1) c += __shfl_xor(c, d2, 64);
    if (c >= Kk) { hi = mid; cntHi = c; } else { lo = mid; }
  }
  {
    unsigned int hu = (unsigned int)hi;
    #pragma unroll
    for (int cc = 0; cc < 8; ++cc) {
      int rc = (cc + l) & 7;
      uint4 k4 = *(const uint4*)(kp + l * 32 + rc * 4);
      unsigned int ks[4] = {k4.x, k4.y, k4.z, k4.w};
      #pragma unroll
      for (int uu = 0; uu < 4; ++uu) {
        #pragma unroll
        for (int hh = 0; hh < 2; ++hh) {
          unsigned int kvv = hh ? (ks[uu] >> 16) : (ks[uu] & 0xffffu);
          if (kvv <= hu) {
            int slot = atomicAdd(&ccntS[w], 1);
            if (slot < CCAPF) candS[w * CCAPF + slot] = l * 64 + (rc * 4 + uu) * 2 + hh;
          }
        }
      }
    }
  }
  __syncthreads();
  const int n = n0 + w;
  const int C = min(cntHi, CCAPF);
  unsigned long long key64 = ~0ULL;
  if (l < C) {
    int mI = candS[w * CCAPF + l];
    const float4* xmf = xb4 + mI * 16;
    float ds = 0.f;
    #pragma unroll
    for (int c = 0; c < 16; c++) {
      float4 a = xb4[n * 16 + c];
      float4 bb = xmf[c];
      float dx = a.x - bb.x, dy = a.y - bb.y, dz = a.z - bb.z, dw2 = a.w - bb.w;
      ds += dx * dx + dy * dy + dz * dz + dw2 * dw2;
    }
    key64 = ((unsigned long long)__float_as_uint(ds) << 32) | (unsigned int)mI;
  }
  float vmax = -FLT_MAX;
  const float* vb = v + (size_t)b * Nn * Ff;
  #pragma unroll
  for (int it = 0; it < Kk; ++it) {
    unsigned long long kmin = key64;
    #pragma unroll
    for (int d2 = 1; d2 < 64; d2 <<= 1) {
      unsigned long long o =
          (unsigned long long)__shfl_xor((long long)kmin, d2, 64);
      kmin = (o < kmin) ? o : kmin;
    }
    int mI = (int)(kmin & 0xffffffffu) & (Nn - 1);
    vmax = fmaxf(vmax, vb[(size_t)mI * 64 + l]);
    if (key64 == kmin) key64 = ~0ULL;
  }
  const size_t oidx = (size_t)(bn0 + w) * 64 + l;
  out[oidx] = u[oidx] + vmax;
}

extern "C" void kernel_launch(void* const* d_in, const int* in_sizes, int n_in,
                              void* d_out, int out_size, void* d_ws,
                              size_t ws_size, hipStream_t stream) {
  const float* x = (const float*)d_in[0];
  const float* W = (const float*)d_in[1];
  const float* bvec = (const float*)d_in[2];
  float* u = (float*)d_ws;                           // 4 MB
  float* v = u + (size_t)Bb * Nn * Ff;               // 4 MB
  float* sq = v + (size_t)Bb * Nn * Ff;              // 64 KB
  unsigned short* xhi = (unsigned short*)(sq + (size_t)Bb * Nn);  // 2 MB
  unsigned short* xlo = xhi + (size_t)Bb * Nn * Ff;               // 2 MB
  unsigned short* keys = xlo + (size_t)Bb * Nn * Ff;              // 128 MB
  float* out = (float*)d_out;
  const size_t need = (size_t)Bb * Nn * Ff * 4 * 2 + (size_t)Bb * Nn * 4 +
                      (size_t)Bb * Nn * Ff * 2 * 2 + (size_t)Bb * Nn * Nn * 2;

  uv_kernel2<<<Bb * Nn / RT1, 256, 0, stream>>>(x, W, bvec, u, v, sq, xhi, xlo);
  if (ws_size >= need) {
    // 4 batches x 128 n-tiles x 2 m-halves = 1024 blocks (R4 launched 256!)
    key_mfma_kernel<<<Bb * Nn / 16, 256, 0, stream>>>(xhi, xlo, sq, keys);
    select_kernel<<<Bb * Nn / 4, 256, 0, stream>>>(x, keys, u, v, out);
  } else {
    knn_kernel<<<Bb * Nn / RTF, 256, 0, stream>>>(x, sq, u, v, out);
  }
}

// Round 6
// 178.237 us; speedup vs baseline: 3.9988x; 1.1517x over previous
//
#include <hip/hip_runtime.h>
#include <float.h>

// EdgeConv: B=4, N=4096, Fin=64, Fout=64, K=20
// out[b,n,o] = u[b,n,o] + max_{m in knn20(n)} v[b,m,o]
//   u = x.(W1-W2)^T + bias ; v = x.W2^T
// knn on d = sq[n] + sq[m] - 2 x_n.x_m (>=0), self excluded.
//
// R6 = R5 + swizzled xhi/xlo: K1 writes bf16 hi/lo in MFMA-fragment order
// (32-row blocks: flat = (n>>5)*2048 + (k>>4)*512 + ((k>>3)&1)*256 +
// (n&31)*8 + (k&7)), so every K2 fragment load is lane-contiguous (1 KB per
// wave instruction) instead of 128-B-strided 16-B reads. Rest unchanged.

constexpr int Bb = 4, Nn = 4096, Ff = 64, Kk = 20;

typedef __attribute__((ext_vector_type(8))) short bf16x8;
typedef __attribute__((ext_vector_type(16))) float f32x16;

__device__ inline unsigned int bf16rn(float f) {
  unsigned int u = __float_as_uint(f);
  return (u + 0x7fffu + ((u >> 16) & 1u)) >> 16;
}

// ---------------- K1: u, v, sq, xhi, xlo (swizzled) ----------------
constexpr int RT1 = 16;  // rows per block

__global__ __launch_bounds__(256) void uv_kernel2(
    const float* __restrict__ x, const float* __restrict__ W,
    const float* __restrict__ bvec, float* __restrict__ u,
    float* __restrict__ v, float* __restrict__ sq,
    unsigned short* __restrict__ xhi, unsigned short* __restrict__ xlo) {
  __shared__ __align__(16) float4 Ws[64 * 33];   // W row o at granules [33o,33o+32)
  __shared__ __align__(16) float4 xs[RT1 * 16];  // x row r at [16r..)
  const int t = threadIdx.x, l = t & 63, w = t >> 6;
  const int bn0 = blockIdx.x * RT1;
  #pragma unroll
  for (int i = 0; i < 8; i++) {
    int f = t + 256 * i;  // f4 index into W (64 rows x 32 f4)
    Ws[(f >> 5) * 33 + (f & 31)] = ((const float4*)W)[f];
  }
  xs[t] = ((const float4*)x)[bn0 * 16 + t];
  __syncthreads();
  // bf16 hi/lo split -> MFMA-fragment-swizzled layout
  #pragma unroll
  for (int i = 0; i < 4; i++) {
    int idx = t + 256 * i;   // 0..1023 within block's 16 rows
    int nloc = idx >> 6;     // row within block
    int k = idx & 63;        // channel
    float val = ((const float*)xs)[idx];
    unsigned int hb = bf16rn(val);
    float fhi = __uint_as_float(hb << 16);
    unsigned int lb = bf16rn(val - fhi);
    int ng = bn0 + nloc;  // global flat row (batch-local swizzle folds in)
    size_t flat = ((size_t)(ng >> 5) << 11) + ((size_t)(k >> 4) << 9) +
                  ((size_t)((k >> 3) & 1) << 8) + ((size_t)(ng & 31) << 3) +
                  (size_t)(k & 7);
    xhi[flat] = (unsigned short)hb;
    xlo[flat] = (unsigned short)lb;
  }
  // sq for rows 4w..4w+3
  #pragma unroll
  for (int i = 0; i < 4; i++) {
    int r = 4 * w + i;
    float val = ((const float*)&xs[r * 16])[l];
    float s = val * val;
    #pragma unroll
    for (int d = 32; d; d >>= 1) s += __shfl_xor(s, d, 64);
    if (l == 0) sq[bn0 + r] = s;
  }
  const int o = l;
  float ua[4] = {0.f, 0.f, 0.f, 0.f}, va[4] = {0.f, 0.f, 0.f, 0.f};
  #pragma unroll
  for (int c = 0; c < 16; c++) {
    float4 w1 = Ws[o * 33 + c];
    float4 w2 = Ws[o * 33 + 16 + c];
    float4 wd;
    wd.x = w1.x - w2.x; wd.y = w1.y - w2.y;
    wd.z = w1.z - w2.z; wd.w = w1.w - w2.w;
    #pragma unroll
    for (int i = 0; i < 4; i++) {
      float4 xv = xs[(4 * w + i) * 16 + c];
      ua[i] += xv.x * wd.x + xv.y * wd.y + xv.z * wd.z + xv.w * wd.w;
      va[i] += xv.x * w2.x + xv.y * w2.y + xv.z * w2.z + xv.w * w2.w;
    }
  }
  float bo = bvec[o];
  #pragma unroll
  for (int i = 0; i < 4; i++) {
    size_t row = (size_t)(bn0 + 4 * w + i);
    u[row * 64 + o] = ua[i] + bo;
    v[row * 64 + o] = va[i];
  }
}

// ---------------- K2: MFMA distance keys (coalesced frag loads) ----------
// Per wave: 32 n-rows x 512 m-cols. Block = 4 waves. Grid 1024 blocks.
// Frag load: base + lane*8 shorts -> 1 KB contiguous per wave instruction.
// C/D: col=lane&31, row=(reg&3)+8*(reg>>2)+4*(lane>>5) [m74/m101].

__global__ __launch_bounds__(256) void key_mfma_kernel(
    const unsigned short* __restrict__ xhi,
    const unsigned short* __restrict__ xlo, const float* __restrict__ sq,
    unsigned short* __restrict__ keys) {
  const int t = threadIdx.x, l = t & 63, w = t >> 6;
  const int blk = blockIdx.x;
  const int b = blk >> 8;
  const int r = blk & 255;
  const int n_base = (r >> 1) * 32;
  const int m0w = (r & 1) * 2048 + w * 512;
  const int col = l & 31, half = l >> 5;

  const unsigned short* xhb = xhi + (size_t)b * Nn * Ff;
  const unsigned short* xlb = xlo + (size_t)b * Nn * Ff;
  const float* sqb = sq + b * Nn;

  bf16x8 Ahi[4], Alo[4];
  #pragma unroll
  for (int ks = 0; ks < 4; ks++) {
    size_t off = ((size_t)((n_base >> 5) * 4 + ks) << 9) + ((size_t)l << 3);
    Ahi[ks] = *(const bf16x8*)(xhb + off);
    Alo[ks] = *(const bf16x8*)(xlb + off);
  }
  float sqn_r[16];
  #pragma unroll
  for (int e = 0; e < 16; e++) {
    int row = (e & 3) + 8 * (e >> 2) + 4 * half;
    sqn_r[e] = sqb[n_base + row];
  }

  for (int j = 0; j < 16; ++j) {
    const int m0 = m0w + 32 * j;
    const int mblk = m0 >> 5;
    bf16x8 Bhi[4], Blo[4];
    #pragma unroll
    for (int ks = 0; ks < 4; ks++) {
      size_t off = ((size_t)(mblk * 4 + ks) << 9) + ((size_t)l << 3);
      Bhi[ks] = *(const bf16x8*)(xhb + off);
      Blo[ks] = *(const bf16x8*)(xlb + off);
    }
    f32x16 acc = {0.f, 0.f, 0.f, 0.f, 0.f, 0.f, 0.f, 0.f,
                  0.f, 0.f, 0.f, 0.f, 0.f, 0.f, 0.f, 0.f};
    #pragma unroll
    for (int ks = 0; ks < 4; ks++) {
      acc = __builtin_amdgcn_mfma_f32_32x32x16_bf16(Ahi[ks], Bhi[ks], acc, 0, 0, 0);
      acc = __builtin_amdgcn_mfma_f32_32x32x16_bf16(Ahi[ks], Blo[ks], acc, 0, 0, 0);
      acc = __builtin_amdgcn_mfma_f32_32x32x16_bf16(Alo[ks], Bhi[ks], acc, 0, 0, 0);
    }
    const int m = m0 + col;
    const float sm = sqb[m];
    #pragma unroll
    for (int e = 0; e < 16; e++) {
      int row = (e & 3) + 8 * (e >> 2) + 4 * half;
      int n = n_base + row;
      float d = fmaxf(sqn_r[e] + sm - 2.0f * acc[e], 0.f);
      unsigned int key = __float_as_uint(d) >> 15;
      if (m == n) key = 0xFFFFu;
      keys[((size_t)(b * Nn + n) << 12) + m] = (unsigned short)key;
    }
  }
}

// ---------------- K3: selection + exact top-20 + output ----------------
__global__ __launch_bounds__(256) void select_kernel(
    const float* __restrict__ x, const unsigned short* __restrict__ keys,
    const float* __restrict__ u, const float* __restrict__ v,
    float* __restrict__ out) {
  __shared__ int candS[4 * 64];
  __shared__ int ccntS[4];
  const int t = threadIdx.x, l = t & 63, w = t >> 6;
  const int row = blockIdx.x * 4 + w;  // flat b*N+n
  const int rowu = __builtin_amdgcn_readfirstlane(row);
  const int b = rowu >> 12, n = rowu & (Nn - 1);
  const uint4* kr = (const uint4*)(keys + (size_t)rowu * Nn);
  uint4 kv[8];
  #pragma unroll
  for (int j = 0; j < 8; j++) kv[j] = kr[j * 64 + l];  // coalesced

  auto countLE = [&](int mid) -> int {
    int c = 0;
    #pragma unroll
    for (int j = 0; j < 8; j++) {
      unsigned int a0 = kv[j].x, a1 = kv[j].y, a2 = kv[j].z, a3 = kv[j].w;
      c += ((int)(a0 & 0xffffu) <= mid) + ((int)(a0 >> 16) <= mid);
      c += ((int)(a1 & 0xffffu) <= mid) + ((int)(a1 >> 16) <= mid);
      c += ((int)(a2 & 0xffffu) <= mid) + ((int)(a2 >> 16) <= mid);
      c += ((int)(a3 & 0xffffu) <= mid) + ((int)(a3 >> 16) <= mid);
    }
    #pragma unroll
    for (int d2 = 1; d2 < 64; d2 <<= 1) c += __shfl_xor(c, d2, 64);
    return c;
  };

  unsigned int mn = 0xffffffffu;
  #pragma unroll
  for (int j = 0; j < 8; j++) {
    unsigned int a0 = kv[j].x, a1 = kv[j].y, a2 = kv[j].z, a3 = kv[j].w;
    mn = min(mn, min(min(a0 & 0xffffu, a0 >> 16), min(a1 & 0xffffu, a1 >> 16)));
    mn = min(mn, min(min(a2 & 0xffffu, a2 >> 16), min(a3 & 0xffffu, a3 >> 16)));
  }
  #pragma unroll
  for (int d2 = 1; d2 < 64; d2 <<= 1)
    mn = min(mn, (unsigned int)__shfl_xor((int)mn, d2, 64));

  // gallop up from min (BOUNDED), then bisect
  int lo = (int)mn - 1;
  int hi = (int)mn + 64;
  if (hi > 65534) hi = 65534;
  int c = countLE(hi);
  int step = 128;
  while (c < Kk && hi < 65534) {
    lo = hi;
    hi += step;
    if (hi > 65534) hi = 65534;
    step <<= 1;
    c = countLE(hi);
  }
  while (c > 44 && hi - lo > 1) {
    int mid = (lo + hi) >> 1;
    int cm = countLE(mid);
    if (cm >= Kk) { hi = mid; c = cm; } else { lo = mid; }
  }
  const int hc = hi + 1;  // +1 quantum margin for approx (bf16-split) keys

  if (l == 0) ccntS[w] = 0;  // in-wave LDS ordering
  #pragma unroll
  for (int j = 0; j < 8; j++) {
    unsigned int a[4] = {kv[j].x, kv[j].y, kv[j].z, kv[j].w};
    #pragma unroll
    for (int e = 0; e < 4; e++) {
      int base = ((j * 64 + l) * 4 + e) * 2;
      if ((int)(a[e] & 0xffffu) <= hc) {
        int slot = atomicAdd(&ccntS[w], 1);
        if (slot < 64) candS[w * 64 + slot] = base;
      }
      if ((int)(a[e] >> 16) <= hc) {
        int slot = atomicAdd(&ccntS[w], 1);
        if (slot < 64) candS[w * 64 + slot] = base + 1;
      }
    }
  }
  int C = ccntS[w];
  if (C > 64) C = 64;

  // exact fp32 distance per candidate
  const float4* xb4 = (const float4*)(x + (size_t)b * Nn * Ff);
  unsigned long long key64 = ~0ULL;
  if (l < C) {
    int mI = candS[w * 64 + l];
    const float4* xmf = xb4 + (size_t)mI * 16;
    float ds = 0.f;
    #pragma unroll
    for (int cc = 0; cc < 16; cc++) {
      float4 a = xb4[(size_t)n * 16 + cc];  // wave-uniform
      float4 bb = xmf[cc];
      float dx = a.x - bb.x, dy = a.y - bb.y, dz = a.z - bb.z, dw2 = a.w - bb.w;
      ds += dx * dx + dy * dy + dz * dz + dw2 * dw2;
    }
    if (mI == n) ds = FLT_MAX;  // belt-and-braces self exclusion
    key64 = ((unsigned long long)__float_as_uint(ds) << 32) | (unsigned int)mI;
  }

  // 20 exact min-extractions fused with v-gather + max
  float vmax = -FLT_MAX;
  const float* vb = v + (size_t)b * Nn * Ff;
  #pragma unroll
  for (int it = 0; it < Kk; ++it) {
    unsigned long long kmin = key64;
    #pragma unroll
    for (int d2 = 1; d2 < 64; d2 <<= 1) {
      unsigned long long o =
          (unsigned long long)__shfl_xor((long long)kmin, d2, 64);
      kmin = (o < kmin) ? o : kmin;
    }
    int mI = (int)(kmin & 0xffffffffu) & (Nn - 1);  // masked: can't fault
    vmax = fmaxf(vmax, vb[(size_t)mI * 64 + l]);
    if (key64 == kmin) key64 = ~0ULL;
  }
  const size_t oidx = (size_t)rowu * 64 + l;
  out[oidx] = u[oidx] + vmax;
}

// ---------------- R2 fallback knn (verified) ----------------
constexpr int RTF = 4;
constexpr int MTF = 64;
constexpr int TPADF = 17;
constexpr int CCAPF = 64;

__global__ __launch_bounds__(256) void knn_kernel(
    const float* __restrict__ x, const float* __restrict__ sq,
    const float* __restrict__ u, const float* __restrict__ v,
    float* __restrict__ out) {
  __shared__ __align__(16) float4 tileS[MTF * TPADF];
  __shared__ __align__(16) unsigned short keysS[RTF * Nn];
  __shared__ int candS[RTF * CCAPF];
  __shared__ int ccntS[RTF];
  const int t = threadIdx.x;
  const int l = t & 63, w = t >> 6;
  const int q = l & 15, g = l >> 4;
  const int bn0 = blockIdx.x * RTF;
  const int b = bn0 >> 12;
  const int n0 = bn0 & (Nn - 1);
  const float4* xb4 = (const float4*)(x + (size_t)b * Nn * Ff);
  const float* sqb = sq + b * Nn;
  if (t < RTF) ccntS[t] = 0;
  float4 xnq[RTF][4];
  #pragma unroll
  for (int r = 0; r < RTF; r++)
    #pragma unroll
    for (int c = 0; c < 4; c++) xnq[r][c] = xb4[(n0 + r) * 16 + 4 * g + c];
  const float sn = sqb[n0 + g];
  const int selfm = n0 + g;
  for (int T = 0; T < Nn / MTF; ++T) {
    __syncthreads();
    #pragma unroll
    for (int i = 0; i < 4; i++) {
      int f = t + 256 * i;
      tileS[(f >> 4) * TPADF + (f & 15)] = xb4[T * 1024 + f];
    }
    __syncthreads();
    const int mrow = 16 * w + q;
    const float4* xmp = &tileS[mrow * TPADF + 4 * g];
    float4 xm0 = xmp[0], xm1 = xmp[1], xm2 = xmp[2], xm3 = xmp[3];
    float dot[RTF];
    #pragma unroll
    for (int r = 0; r < RTF; r++) {
      float4 a0 = xnq[r][0], a1 = xnq[r][1], a2 = xnq[r][2], a3 = xnq[r][3];
      dot[r] = a0.x * xm0.x + a0.y * xm0.y + a0.z * xm0.z + a0.w * xm0.w +
               a1.x * xm1.x + a1.y * xm1.y + a1.z * xm1.z + a1.w * xm1.w +
               a2.x * xm2.x + a2.y * xm2.y + a2.z * xm2.z + a2.w * xm2.w +
               a3.x * xm3.x + a3.y * xm3.y + a3.z * xm3.z + a3.w * xm3.w;
    }
    #pragma unroll
    for (int r = 0; r < RTF; r++) {
      dot[r] += __shfl_xor(dot[r], 16, 64);
      dot[r] += __shfl_xor(dot[r], 32, 64);
    }
    float dg = (g == 0) ? dot[0] : (g == 1) ? dot[1] : (g == 2) ? dot[2] : dot[3];
    int m = T * MTF + mrow;
    float d = fmaxf(fmaf(-2.f, dg, sqb[m] + sn), 0.f);
    unsigned int key = __float_as_uint(d) >> 15;
    if (m == selfm) key = 0xFFFFu;
    keysS[g * Nn + m] = (unsigned short)key;
  }
  __syncthreads();
  const unsigned int* kp = (const unsigned int*)&keysS[w * Nn];
  int lo = -1, hi = 65535, cntHi = Nn;
  while (cntHi > 48 && hi - lo > 1) {
    int mid = (lo + hi) >> 1;
    unsigned int midu = (unsigned int)mid;
    int c = 0;
    #pragma unroll
    for (int cc = 0; cc < 8; ++cc) {
      int rc = (cc + l) & 7;
      uint4 k4 = *(const uint4*)(kp + l * 32 + rc * 4);
      c += ((k4.x & 0xffffu) <= midu) + ((k4.x >> 16) <= midu);
      c += ((k4.y & 0xffffu) <= midu) + ((k4.y >> 16) <= midu);
      c += ((k4.z & 0xffffu) <= midu) + ((k4.z >> 16) <= midu);
      c += ((k4.w & 0xffffu) <= midu) + ((k4.w >> 16) <= midu);
    }
    #pragma unroll
    for (int d2 = 1; d2 < 64; d2 <<= 1) c += __shfl_xor(c, d2, 64);
    if (c >= Kk) { hi = mid; cntHi = c; } else { lo = mid; }
  }
  {
    unsigned int hu = (unsigned int)hi;
    #pragma unroll
    for (int cc = 0; cc < 8; ++cc) {
      int rc = (cc + l) & 7;
      uint4 k4 = *(const uint4*)(kp + l * 32 + rc * 4);
      unsigned int ks[4] = {k4.x, k4.y, k4.z, k4.w};
      #pragma unroll
      for (int uu = 0; uu < 4; ++uu) {
        #pragma unroll
        for (int hh = 0; hh < 2; ++hh) {
          unsigned int kvv = hh ? (ks[uu] >> 16) : (ks[uu] & 0xffffu);
          if (kvv <= hu) {
            int slot = atomicAdd(&ccntS[w], 1);
            if (slot < CCAPF) candS[w * CCAPF + slot] = l * 64 + (rc * 4 + uu) * 2 + hh;
          }
        }
      }
    }
  }
  __syncthreads();
  const int n = n0 + w;
  const int C = min(cntHi, CCAPF);
  unsigned long long key64 = ~0ULL;
  if (l < C) {
    int mI = candS[w * CCAPF + l];
    const float4* xmf = xb4 + mI * 16;
    float ds = 0.f;
    #pragma unroll
    for (int c = 0; c < 16; c++) {
      float4 a = xb4[n * 16 + c];
      float4 bb = xmf[c];
      float dx = a.x - bb.x, dy = a.y - bb.y, dz = a.z - bb.z, dw2 = a.w - bb.w;
      ds += dx * dx + dy * dy + dz * dz + dw2 * dw2;
    }
    key64 = ((unsigned long long)__float_as_uint(ds) << 32) | (unsigned int)mI;
  }
  float vmax = -FLT_MAX;
  const float* vb = v + (size_t)b * Nn * Ff;
  #pragma unroll
  for (int it = 0; it < Kk; ++it) {
    unsigned long long kmin = key64;
    #pragma unroll
    for (int d2 = 1; d2 < 64; d2 <<= 1) {
      unsigned long long o =
          (unsigned long long)__shfl_xor((long long)kmin, d2, 64);
      kmin = (o < kmin) ? o : kmin;
    }
    int mI = (int)(kmin & 0xffffffffu) & (Nn - 1);
    vmax = fmaxf(vmax, vb[(size_t)mI * 64 + l]);
    if (key64 == kmin) key64 = ~0ULL;
  }
  const size_t oidx = (size_t)(bn0 + w) * 64 + l;
  out[oidx] = u[oidx] + vmax;
}

extern "C" void kernel_launch(void* const* d_in, const int* in_sizes, int n_in,
                              void* d_out, int out_size, void* d_ws,
                              size_t ws_size, hipStream_t stream) {
  const float* x = (const float*)d_in[0];
  const float* W = (const float*)d_in[1];
  const float* bvec = (const float*)d_in[2];
  float* u = (float*)d_ws;                           // 4 MB
  float* v = u + (size_t)Bb * Nn * Ff;               // 4 MB
  float* sq = v + (size_t)Bb * Nn * Ff;              // 64 KB
  unsigned short* xhi = (unsigned short*)(sq + (size_t)Bb * Nn);  // 2 MB
  unsigned short* xlo = xhi + (size_t)Bb * Nn * Ff;               // 2 MB
  unsigned short* keys = xlo + (size_t)Bb * Nn * Ff;              // 128 MB
  float* out = (float*)d_out;
  const size_t need = (size_t)Bb * Nn * Ff * 4 * 2 + (size_t)Bb * Nn * 4 +
                      (size_t)Bb * Nn * Ff * 2 * 2 + (size_t)Bb * Nn * Nn * 2;

  uv_kernel2<<<Bb * Nn / RT1, 256, 0, stream>>>(x, W, bvec, u, v, sq, xhi, xlo);
  if (ws_size >= need) {
    // 4 batches x 128 n-tiles x 2 m-halves = 1024 blocks
    key_mfma_kernel<<<Bb * Nn / 16, 256, 0, stream>>>(xhi, xlo, sq, keys);
    select_kernel<<<Bb * Nn / 4, 256, 0, stream>>>(x, keys, u, v, out);
  } else {
    knn_kernel<<<Bb * Nn / RTF, 256, 0, stream>>>(x, sq, u, v, out);
  }
}